// Round 1
// baseline (3394.068 us; speedup 1.0000x reference)
//
#include <hip/hip_runtime.h>

// SignNet GINE: 3 layers, signs batched as 2N interleaved rows (2i=+x, 2i+1=-x).
constexpr int DHID = 128;

__global__ __launch_bounds__(256)
void init_h0(const float* __restrict__ x, float* __restrict__ H0, int n) {
    int i = blockIdx.x * 256 + threadIdx.x;   // over N*16
    if (i < n * 16) {
        int r = i >> 4, c = i & 15;
        float v = x[i];
        H0[(size_t)(2 * r) * 16 + c] = v;
        H0[(size_t)(2 * r + 1) * 16 + c] = -v;
    }
}

// S[i][c] = H3[2i][c] + H3[2i+1][c], d=64
__global__ __launch_bounds__(256)
void sum_signs(const float* __restrict__ H3, float* __restrict__ S, int n) {
    int i = blockIdx.x * 256 + threadIdx.x;   // over N*64
    if (i < n * 64) {
        int r = i >> 6;
        S[i] = H3[i + (size_t)r * 64] + H3[i + (size_t)r * 64 + 64];
    }
}

// Layer 0 edge pass: din=16. 16 lanes per edge, 4 edges per wave.
__global__ __launch_bounds__(256)
void edge_pass16(const float* __restrict__ EA, const int* __restrict__ SRC,
                 const int* __restrict__ DST, const float* __restrict__ WE,
                 const float* __restrict__ BE, const float* __restrict__ H,
                 float* __restrict__ AGG, int E_) {
    const int tid = threadIdx.x;
    const int c = tid & 15;
    float w[16];
#pragma unroll
    for (int k = 0; k < 16; ++k) w[k] = WE[k * 16 + c];
    const float bev = BE[c];
    const int epb = 256 / 16;  // 16 edges per block pass
    for (long e = (long)blockIdx.x * epb + (tid >> 4); e < E_;
         e += (long)gridDim.x * epb) {
        int el = (int)e;
        int src = SRC[el], dst = DST[el];
        const float4* ea4 = (const float4*)(EA + (size_t)el * 16);
        float4 a0 = ea4[0], a1 = ea4[1], a2 = ea4[2], a3 = ea4[3];
        float av[16] = {a0.x, a0.y, a0.z, a0.w, a1.x, a1.y, a1.z, a1.w,
                        a2.x, a2.y, a2.z, a2.w, a3.x, a3.y, a3.z, a3.w};
        float acc = bev;
#pragma unroll
        for (int k = 0; k < 16; ++k) acc += av[k] * w[k];
        // both signs: rows 2*src, 2*src+1
#pragma unroll
        for (int s = 0; s < 2; ++s) {
            float m = fmaxf(H[(size_t)(2 * src + s) * 16 + c] + acc, 0.f);
            atomicAdd(&AGG[(size_t)(2 * dst + s) * 16 + c], m);
        }
    }
}

// Layers 1,2 edge pass: din=128. One wave per edge; lane handles cols c, c+64.
__global__ __launch_bounds__(256)
void edge_pass128(const float* __restrict__ EA, const int* __restrict__ SRC,
                  const int* __restrict__ DST, const float* __restrict__ WE,
                  const float* __restrict__ BE, const float* __restrict__ H,
                  float* __restrict__ AGG, int E_) {
    const int tid = threadIdx.x;
    const int lane = tid & 63;
    const int wid = tid >> 6;
    const int c = lane;  // cols c and c+64
    float w0[16], w1[16];
#pragma unroll
    for (int k = 0; k < 16; ++k) {
        w0[k] = WE[k * 128 + c];
        w1[k] = WE[k * 128 + c + 64];
    }
    const float be0v = BE[c], be1v = BE[c + 64];
    for (long e = (long)blockIdx.x * 4 + wid; e < E_; e += (long)gridDim.x * 4) {
        int el = (int)e;
        int src = SRC[el], dst = DST[el];
        const float4* ea4 = (const float4*)(EA + (size_t)el * 16);
        float4 a0 = ea4[0], a1 = ea4[1], a2 = ea4[2], a3 = ea4[3];
        float av[16] = {a0.x, a0.y, a0.z, a0.w, a1.x, a1.y, a1.z, a1.w,
                        a2.x, a2.y, a2.z, a2.w, a3.x, a3.y, a3.z, a3.w};
        float e0 = be0v, e1 = be1v;
#pragma unroll
        for (int k = 0; k < 16; ++k) {
            e0 += av[k] * w0[k];
            e1 += av[k] * w1[k];
        }
#pragma unroll
        for (int s = 0; s < 2; ++s) {
            const float* hrow = H + (size_t)(2 * src + s) * 128;
            float* arow = AGG + (size_t)(2 * dst + s) * 128;
            float m0 = fmaxf(hrow[c] + e0, 0.f);
            float m1 = fmaxf(hrow[c + 64] + e1, 0.f);
            atomicAdd(arow + c, m0);
            atomicAdd(arow + c + 64, m1);
        }
    }
}

// Fused node MLP: OUT = maybe_relu( relu((X [+AGG]) @ W1 + b1) @ W2 + b2 )
// DH = 128 always. 32-row tiles; W1 staged in LDS; W2 streamed from L2.
template <int DIN, int DOUT, bool RELU_OUT, bool HAS_AGG>
__global__ __launch_bounds__(256)
void node_mlp(const float* __restrict__ X, const float* __restrict__ AGG,
              const float* __restrict__ W1, const float* __restrict__ B1,
              const float* __restrict__ W2, const float* __restrict__ B2,
              float* __restrict__ OUT, int rows) {
    __shared__ float sW1[DIN * DHID];
    __shared__ float sX[32 * DIN];
    __shared__ float sH[32 * DHID];
    __shared__ float sB1[DHID];
    const int tid = threadIdx.x;
    for (int i = tid; i < DIN * DHID; i += 256) sW1[i] = W1[i];
    if (tid < DHID) sB1[tid] = B1[tid];

    for (int row0 = blockIdx.x * 32; row0 < rows; row0 += gridDim.x * 32) {
        __syncthreads();  // sW1 staged (iter 0); sX/sH free (prev iter done)
        // stage X (+AGG) tile
        for (int i = tid; i < 32 * DIN; i += 256) {
            int r = i / DIN, k = i % DIN;
            int gr = row0 + r;
            float v = 0.f;
            if (gr < rows) {
                v = X[(size_t)gr * DIN + k];
                if (HAS_AGG) v += AGG[(size_t)gr * DIN + k];
            }
            sX[i] = v;
        }
        __syncthreads();
        // hidden = relu(sX @ W1 + b1): lane cols (c, c+64), rows r0+4j
        {
            const int c = tid & 63;
            const int r0 = tid >> 6;
            float acc[8][2];
#pragma unroll
            for (int j = 0; j < 8; ++j) {
                acc[j][0] = sB1[c];
                acc[j][1] = sB1[c + 64];
            }
#pragma unroll
            for (int k = 0; k < DIN; ++k) {
                float wa = sW1[k * DHID + c];
                float wb = sW1[k * DHID + c + 64];
#pragma unroll
                for (int j = 0; j < 8; ++j) {
                    float xv = sX[(r0 + 4 * j) * DIN + k];
                    acc[j][0] += xv * wa;
                    acc[j][1] += xv * wb;
                }
            }
#pragma unroll
            for (int j = 0; j < 8; ++j) {
                int r = r0 + 4 * j;
                sH[r * DHID + c] = fmaxf(acc[j][0], 0.f);
                sH[r * DHID + c + 64] = fmaxf(acc[j][1], 0.f);
            }
        }
        __syncthreads();
        // out = sH @ W2 + b2
        {
            constexpr int HALF = DOUT / 2;   // lanes per row-group (2 cols each)
            constexpr int RP = 256 / HALF;   // rows in parallel
            constexpr int ITER = 32 / RP;
            const int c = tid % HALF;
            const int r0 = tid / HALF;
            float acc[ITER][2];
            const float bz0 = B2[c], bz1 = B2[c + HALF];
#pragma unroll
            for (int j = 0; j < ITER; ++j) {
                acc[j][0] = bz0;
                acc[j][1] = bz1;
            }
#pragma unroll 4
            for (int k = 0; k < DHID; ++k) {
                float wa = W2[k * DOUT + c];
                float wb = W2[k * DOUT + c + HALF];
#pragma unroll
                for (int j = 0; j < ITER; ++j) {
                    float hv = sH[(r0 + RP * j) * DHID + k];
                    acc[j][0] += hv * wa;
                    acc[j][1] += hv * wb;
                }
            }
#pragma unroll
            for (int j = 0; j < ITER; ++j) {
                int gr = row0 + r0 + RP * j;
                if (gr < rows) {
                    float o0 = acc[j][0], o1 = acc[j][1];
                    if (RELU_OUT) {
                        o0 = fmaxf(o0, 0.f);
                        o1 = fmaxf(o1, 0.f);
                    }
                    OUT[(size_t)gr * DOUT + c] = o0;
                    OUT[(size_t)gr * DOUT + c + HALF] = o1;
                }
            }
        }
    }
}

extern "C" void kernel_launch(void* const* d_in, const int* in_sizes, int n_in,
                              void* d_out, int out_size, void* d_ws, size_t ws_size,
                              hipStream_t stream) {
    const float* x = (const float*)d_in[0];
    const float* ea = (const float*)d_in[1];
    const int* esrc = (const int*)d_in[2];
    const int* edst = (const int*)d_in[3];
    const float* we0 = (const float*)d_in[4];
    const float* be0 = (const float*)d_in[5];
    const float* w10 = (const float*)d_in[6];
    const float* b10 = (const float*)d_in[7];
    const float* w20 = (const float*)d_in[8];
    const float* b20 = (const float*)d_in[9];
    const float* we1 = (const float*)d_in[10];
    const float* be1 = (const float*)d_in[11];
    const float* w11 = (const float*)d_in[12];
    const float* b11 = (const float*)d_in[13];
    const float* w21 = (const float*)d_in[14];
    const float* b21 = (const float*)d_in[15];
    const float* we2 = (const float*)d_in[16];
    const float* be2 = (const float*)d_in[17];
    const float* w12 = (const float*)d_in[18];
    const float* b12 = (const float*)d_in[19];
    const float* w22 = (const float*)d_in[20];
    const float* b22 = (const float*)d_in[21];
    const float* rw1 = (const float*)d_in[22];
    const float* rb1 = (const float*)d_in[23];
    const float* rw2 = (const float*)d_in[24];
    const float* rb2 = (const float*)d_in[25];

    const int N = in_sizes[0] / 16;
    const int E = in_sizes[2];
    const int M = 2 * N;  // batched sign rows, interleaved

    float* HA = (float*)d_ws;                  // M*128
    float* HB = HA + (size_t)M * 128;          // M*128
    float* AG = HB + (size_t)M * 128;          // M*128 (also reused as S)

    const int ntiles = (M + 31) / 32;

    // H0 (M x 16)
    init_h0<<<(N * 16 + 255) / 256, 256, 0, stream>>>(x, HA, N);

    // ---- layer 0 (din=16 -> 128) ----
    hipMemsetAsync(AG, 0, (size_t)M * 16 * sizeof(float), stream);
    edge_pass16<<<1024, 256, 0, stream>>>(ea, esrc, edst, we0, be0, HA, AG, E);
    node_mlp<16, 128, true, true><<<ntiles, 256, 0, stream>>>(
        HA, AG, w10, b10, w20, b20, HB, M);

    // ---- layer 1 (128 -> 128) ----
    hipMemsetAsync(AG, 0, (size_t)M * 128 * sizeof(float), stream);
    edge_pass128<<<2048, 256, 0, stream>>>(ea, esrc, edst, we1, be1, HB, AG, E);
    node_mlp<128, 128, true, true><<<ntiles, 256, 0, stream>>>(
        HB, AG, w11, b11, w21, b21, HA, M);

    // ---- layer 2 (128 -> 64) ----
    hipMemsetAsync(AG, 0, (size_t)M * 128 * sizeof(float), stream);
    edge_pass128<<<2048, 256, 0, stream>>>(ea, esrc, edst, we2, be2, HA, AG, E);
    node_mlp<128, 64, false, true><<<ntiles, 256, 0, stream>>>(
        HA, AG, w12, b12, w22, b22, HB, M);

    // ---- sign sum + readout (64 -> 128 -> 16) ----
    sum_signs<<<(N * 64 + 255) / 256, 256, 0, stream>>>(HB, AG, N);
    node_mlp<64, 16, false, false><<<(N + 31) / 32, 256, 0, stream>>>(
        AG, nullptr, rw1, rb1, rw2, rb2, (float*)d_out, N);
}

// Round 2
// 1619.827 us; speedup vs baseline: 2.0953x; 2.0953x over previous
//
#include <hip/hip_runtime.h>

// SignNet GINE: 3 layers, signs batched as 2N interleaved rows (2i=+x, 2i+1=-x).
// Edge aggregation via device-built CSR + per-node gather (no f32 atomics).
constexpr int DHID = 128;

__global__ __launch_bounds__(256)
void init_h0(const float* __restrict__ x, float* __restrict__ H0, int n) {
    int i = blockIdx.x * 256 + threadIdx.x;   // over N*16
    if (i < n * 16) {
        int r = i >> 4, c = i & 15;
        float v = x[i];
        H0[(size_t)(2 * r) * 16 + c] = v;
        H0[(size_t)(2 * r + 1) * 16 + c] = -v;
    }
}

// S[i][c] = H3[2i][c] + H3[2i+1][c], d=64
__global__ __launch_bounds__(256)
void sum_signs(const float* __restrict__ H3, float* __restrict__ S, int n) {
    int i = blockIdx.x * 256 + threadIdx.x;   // over N*64
    if (i < n * 64) {
        int r = i >> 6;
        S[i] = H3[i + (size_t)r * 64] + H3[i + (size_t)r * 64 + 64];
    }
}

// ---------------- CSR build ----------------
__global__ __launch_bounds__(256)
void csr_count(const int* __restrict__ DST, int* __restrict__ deg, int E_) {
    int e = blockIdx.x * 256 + threadIdx.x;
    if (e < E_) atomicAdd(&deg[DST[e]], 1);
}

// exclusive scan, 256-wide chunks
__global__ __launch_bounds__(256)
void scan1(const int* __restrict__ deg, int* __restrict__ off,
           int* __restrict__ bsum, int n) {
    __shared__ int s[256];
    int tid = threadIdx.x;
    int i = blockIdx.x * 256 + tid;
    int v = (i < n) ? deg[i] : 0;
    s[tid] = v;
    __syncthreads();
    for (int d = 1; d < 256; d <<= 1) {
        int t = (tid >= d) ? s[tid - d] : 0;
        __syncthreads();
        if (tid >= d) s[tid] += t;
        __syncthreads();
    }
    if (i < n) off[i] = s[tid] - v;      // exclusive
    if (tid == 255) bsum[blockIdx.x] = s[255];
}

__global__ __launch_bounds__(256)
void scan2(int* __restrict__ bsum, int nb) {
    __shared__ int s[256];
    int tid = threadIdx.x;
    int v = (tid < nb) ? bsum[tid] : 0;
    s[tid] = v;
    __syncthreads();
    for (int d = 1; d < 256; d <<= 1) {
        int t = (tid >= d) ? s[tid - d] : 0;
        __syncthreads();
        if (tid >= d) s[tid] += t;
        __syncthreads();
    }
    if (tid < nb) bsum[tid] = s[tid] - v;  // exclusive
}

__global__ __launch_bounds__(256)
void scan3(int* __restrict__ off, int* __restrict__ pos,
           const int* __restrict__ bsum, const int* __restrict__ deg, int n) {
    int i = blockIdx.x * 256 + threadIdx.x;
    if (i < n) {
        int o = off[i] + bsum[blockIdx.x];
        off[i] = o;
        pos[i] = o;
        if (i == n - 1) off[n] = o + deg[i];
    }
}

__global__ __launch_bounds__(256)
void csr_fill(const int* __restrict__ SRC, const int* __restrict__ DST,
              int* __restrict__ pos, int2* __restrict__ csr, int E_) {
    int e = blockIdx.x * 256 + threadIdx.x;
    if (e < E_) {
        int d = DST[e];
        int j = atomicAdd(&pos[d], 1);
        csr[j] = make_int2(SRC[e], e);
    }
}

// ---------------- gather aggregation ----------------
// din=128: one wave per node; lane handles cols c, c+64 for both signs.
__global__ __launch_bounds__(256)
void agg_gather128(const int2* __restrict__ CSR, const int* __restrict__ OFF,
                   const float* __restrict__ EA, const float* __restrict__ WE,
                   const float* __restrict__ BE, const float* __restrict__ H,
                   float* __restrict__ AGG, int n) {
    const int lane = threadIdx.x & 63;
    const int node = blockIdx.x * 4 + (threadIdx.x >> 6);
    if (node >= n) return;
    const int c = lane;
    float w0[16], w1[16];
#pragma unroll
    for (int k = 0; k < 16; ++k) {
        w0[k] = WE[k * 128 + c];
        w1[k] = WE[k * 128 + c + 64];
    }
    const float be0 = BE[c], be1 = BE[c + 64];
    float a00 = 0.f, a01 = 0.f, a10 = 0.f, a11 = 0.f;  // [sign][half]
    const int j0 = OFF[node], j1 = OFF[node + 1];
    for (int j = j0; j < j1; ++j) {
        int2 se = CSR[j];
        const float4* ea4 = (const float4*)(EA + (size_t)se.y * 16);
        float4 q0 = ea4[0], q1 = ea4[1], q2 = ea4[2], q3 = ea4[3];
        float av[16] = {q0.x, q0.y, q0.z, q0.w, q1.x, q1.y, q1.z, q1.w,
                        q2.x, q2.y, q2.z, q2.w, q3.x, q3.y, q3.z, q3.w};
        float e0 = be0, e1 = be1;
#pragma unroll
        for (int k = 0; k < 16; ++k) {
            e0 += av[k] * w0[k];
            e1 += av[k] * w1[k];
        }
        const float* h0 = H + (size_t)(2 * se.x) * 128;  // rows 2src, 2src+1 contiguous
        a00 += fmaxf(h0[c] + e0, 0.f);
        a01 += fmaxf(h0[c + 64] + e1, 0.f);
        a10 += fmaxf(h0[128 + c] + e0, 0.f);
        a11 += fmaxf(h0[128 + c + 64] + e1, 0.f);
    }
    float* arow = AGG + (size_t)(2 * node) * 128;
    arow[c] = a00;
    arow[c + 64] = a01;
    arow[128 + c] = a10;
    arow[128 + c + 64] = a11;
}

// din=16: half-wave (32 lanes) per node: s = (l>>4)&1, c = l&15.
__global__ __launch_bounds__(256)
void agg_gather16(const int2* __restrict__ CSR, const int* __restrict__ OFF,
                  const float* __restrict__ EA, const float* __restrict__ WE,
                  const float* __restrict__ BE, const float* __restrict__ H,
                  float* __restrict__ AGG, int n) {
    const int l = threadIdx.x & 31;
    const int node = blockIdx.x * 8 + (threadIdx.x >> 5);
    if (node >= n) return;
    const int s = l >> 4;
    const int c = l & 15;
    float w[16];
#pragma unroll
    for (int k = 0; k < 16; ++k) w[k] = WE[k * 16 + c];
    const float bev = BE[c];
    float acc = 0.f;
    const int j0 = OFF[node], j1 = OFF[node + 1];
    for (int j = j0; j < j1; ++j) {
        int2 se = CSR[j];
        const float4* ea4 = (const float4*)(EA + (size_t)se.y * 16);
        float4 q0 = ea4[0], q1 = ea4[1], q2 = ea4[2], q3 = ea4[3];
        float av[16] = {q0.x, q0.y, q0.z, q0.w, q1.x, q1.y, q1.z, q1.w,
                        q2.x, q2.y, q2.z, q2.w, q3.x, q3.y, q3.z, q3.w};
        float ec = bev;
#pragma unroll
        for (int k = 0; k < 16; ++k) ec += av[k] * w[k];
        float hv = H[(size_t)(2 * se.x + s) * 16 + c];
        acc += fmaxf(hv + ec, 0.f);
    }
    AGG[(size_t)(2 * node + s) * 16 + c] = acc;
}

// Fused node MLP: OUT = maybe_relu( relu((X [+AGG]) @ W1 + b1) @ W2 + b2 )
template <int DIN, int DOUT, bool RELU_OUT, bool HAS_AGG>
__global__ __launch_bounds__(256)
void node_mlp(const float* __restrict__ X, const float* __restrict__ AGG,
              const float* __restrict__ W1, const float* __restrict__ B1,
              const float* __restrict__ W2, const float* __restrict__ B2,
              float* __restrict__ OUT, int rows) {
    __shared__ float sW1[DIN * DHID];
    __shared__ float sX[32 * DIN];
    __shared__ float sH[32 * DHID];
    __shared__ float sB1[DHID];
    const int tid = threadIdx.x;
    for (int i = tid; i < DIN * DHID; i += 256) sW1[i] = W1[i];
    if (tid < DHID) sB1[tid] = B1[tid];

    for (int row0 = blockIdx.x * 32; row0 < rows; row0 += gridDim.x * 32) {
        __syncthreads();
        for (int i = tid; i < 32 * DIN; i += 256) {
            int r = i / DIN, k = i % DIN;
            int gr = row0 + r;
            float v = 0.f;
            if (gr < rows) {
                v = X[(size_t)gr * DIN + k];
                if (HAS_AGG) v += AGG[(size_t)gr * DIN + k];
            }
            sX[i] = v;
        }
        __syncthreads();
        {
            const int c = tid & 63;
            const int r0 = tid >> 6;
            float acc[8][2];
#pragma unroll
            for (int j = 0; j < 8; ++j) {
                acc[j][0] = sB1[c];
                acc[j][1] = sB1[c + 64];
            }
#pragma unroll
            for (int k = 0; k < DIN; ++k) {
                float wa = sW1[k * DHID + c];
                float wb = sW1[k * DHID + c + 64];
#pragma unroll
                for (int j = 0; j < 8; ++j) {
                    float xv = sX[(r0 + 4 * j) * DIN + k];
                    acc[j][0] += xv * wa;
                    acc[j][1] += xv * wb;
                }
            }
#pragma unroll
            for (int j = 0; j < 8; ++j) {
                int r = r0 + 4 * j;
                sH[r * DHID + c] = fmaxf(acc[j][0], 0.f);
                sH[r * DHID + c + 64] = fmaxf(acc[j][1], 0.f);
            }
        }
        __syncthreads();
        {
            constexpr int HALF = DOUT / 2;
            constexpr int RP = 256 / HALF;
            constexpr int ITER = 32 / RP;
            const int c = tid % HALF;
            const int r0 = tid / HALF;
            float acc[ITER][2];
            const float bz0 = B2[c], bz1 = B2[c + HALF];
#pragma unroll
            for (int j = 0; j < ITER; ++j) {
                acc[j][0] = bz0;
                acc[j][1] = bz1;
            }
#pragma unroll 4
            for (int k = 0; k < DHID; ++k) {
                float wa = W2[k * DOUT + c];
                float wb = W2[k * DOUT + c + HALF];
#pragma unroll
                for (int j = 0; j < ITER; ++j) {
                    float hv = sH[(r0 + RP * j) * DHID + k];
                    acc[j][0] += hv * wa;
                    acc[j][1] += hv * wb;
                }
            }
#pragma unroll
            for (int j = 0; j < ITER; ++j) {
                int gr = row0 + r0 + RP * j;
                if (gr < rows) {
                    float o0 = acc[j][0], o1 = acc[j][1];
                    if (RELU_OUT) {
                        o0 = fmaxf(o0, 0.f);
                        o1 = fmaxf(o1, 0.f);
                    }
                    OUT[(size_t)gr * DOUT + c] = o0;
                    OUT[(size_t)gr * DOUT + c + HALF] = o1;
                }
            }
        }
    }
}

extern "C" void kernel_launch(void* const* d_in, const int* in_sizes, int n_in,
                              void* d_out, int out_size, void* d_ws, size_t ws_size,
                              hipStream_t stream) {
    const float* x = (const float*)d_in[0];
    const float* ea = (const float*)d_in[1];
    const int* esrc = (const int*)d_in[2];
    const int* edst = (const int*)d_in[3];
    const float* we0 = (const float*)d_in[4];
    const float* be0 = (const float*)d_in[5];
    const float* w10 = (const float*)d_in[6];
    const float* b10 = (const float*)d_in[7];
    const float* w20 = (const float*)d_in[8];
    const float* b20 = (const float*)d_in[9];
    const float* we1 = (const float*)d_in[10];
    const float* be1 = (const float*)d_in[11];
    const float* w11 = (const float*)d_in[12];
    const float* b11 = (const float*)d_in[13];
    const float* w21 = (const float*)d_in[14];
    const float* b21 = (const float*)d_in[15];
    const float* we2 = (const float*)d_in[16];
    const float* be2 = (const float*)d_in[17];
    const float* w12 = (const float*)d_in[18];
    const float* b12 = (const float*)d_in[19];
    const float* w22 = (const float*)d_in[20];
    const float* b22 = (const float*)d_in[21];
    const float* rw1 = (const float*)d_in[22];
    const float* rb1 = (const float*)d_in[23];
    const float* rw2 = (const float*)d_in[24];
    const float* rb2 = (const float*)d_in[25];

    const int N = in_sizes[0] / 16;
    const int E = in_sizes[2];
    const int M = 2 * N;

    float* HA = (float*)d_ws;                  // M*128
    float* HB = HA + (size_t)M * 128;          // M*128
    float* AG = HB + (size_t)M * 128;          // M*128
    int* deg = (int*)(AG + (size_t)M * 128);   // N
    int* off = deg + N;                        // N+1
    int* pos = off + N + 1;                    // N
    int* bsum = pos + N;                       // 256
    int2* csr = (int2*)(bsum + 256);           // E

    const int ntiles = (M + 31) / 32;
    const int eblocks = (E + 255) / 256;
    const int nblocks = (N + 255) / 256;

    // ---- CSR build (once; shared by all 3 layers) ----
    hipMemsetAsync(deg, 0, (size_t)N * sizeof(int), stream);
    csr_count<<<eblocks, 256, 0, stream>>>(edst, deg, E);
    scan1<<<nblocks, 256, 0, stream>>>(deg, off, bsum, N);
    scan2<<<1, 256, 0, stream>>>(bsum, nblocks);
    scan3<<<nblocks, 256, 0, stream>>>(off, pos, bsum, deg, N);
    csr_fill<<<eblocks, 256, 0, stream>>>(esrc, edst, pos, csr, E);

    // H0 (M x 16)
    init_h0<<<(N * 16 + 255) / 256, 256, 0, stream>>>(x, HA, N);

    // ---- layer 0 (din=16 -> 128) ----
    agg_gather16<<<(N + 7) / 8, 256, 0, stream>>>(csr, off, ea, we0, be0, HA, AG, N);
    node_mlp<16, 128, true, true><<<ntiles, 256, 0, stream>>>(
        HA, AG, w10, b10, w20, b20, HB, M);

    // ---- layer 1 (128 -> 128) ----
    agg_gather128<<<(N + 3) / 4, 256, 0, stream>>>(csr, off, ea, we1, be1, HB, AG, N);
    node_mlp<128, 128, true, true><<<ntiles, 256, 0, stream>>>(
        HB, AG, w11, b11, w21, b21, HA, M);

    // ---- layer 2 (128 -> 64) ----
    agg_gather128<<<(N + 3) / 4, 256, 0, stream>>>(csr, off, ea, we2, be2, HA, AG, N);
    node_mlp<128, 64, false, true><<<ntiles, 256, 0, stream>>>(
        HA, AG, w12, b12, w22, b22, HB, M);

    // ---- sign sum + readout (64 -> 128 -> 16) ----
    sum_signs<<<(N * 64 + 255) / 256, 256, 0, stream>>>(HB, AG, N);
    node_mlp<64, 16, false, false><<<(N + 31) / 32, 256, 0, stream>>>(
        AG, nullptr, rw1, rb1, rw2, rb2, (float*)d_out, N);
}

// Round 3
// 1213.400 us; speedup vs baseline: 2.7972x; 1.3349x over previous
//
#include <hip/hip_runtime.h>

// SignNet GINE: 3 layers, signs batched as 2N interleaved rows (2i=+x, 2i+1=-x).
// CSR gather aggregation; gather path reads bf16 H + CSR-sorted bf16 edge attrs.
constexpr int DHID = 128;

__device__ __forceinline__ float b2f(unsigned short u) {
    union { unsigned int i; float f; } v;
    v.i = ((unsigned int)u) << 16;
    return v.f;
}
__device__ __forceinline__ unsigned short f2b(float f) {
    union { float f; unsigned int i; } v;
    v.f = f;
    unsigned int x = v.i;
    return (unsigned short)((x + 0x7fff + ((x >> 16) & 1)) >> 16);
}
__device__ __forceinline__ unsigned int pack2(float a, float b) {
    return (unsigned int)f2b(a) | ((unsigned int)f2b(b) << 16);
}

__global__ __launch_bounds__(256)
void init_h0(const float* __restrict__ x, float* __restrict__ H0,
             unsigned short* __restrict__ H0B, int n) {
    int i = blockIdx.x * 256 + threadIdx.x;   // over N*16
    if (i < n * 16) {
        int r = i >> 4, c = i & 15;
        float v = x[i];
        H0[(size_t)(2 * r) * 16 + c] = v;
        H0[(size_t)(2 * r + 1) * 16 + c] = -v;
        H0B[(size_t)(2 * r) * 16 + c] = f2b(v);
        H0B[(size_t)(2 * r + 1) * 16 + c] = f2b(-v);
    }
}

__global__ __launch_bounds__(256)
void sum_signs(const float* __restrict__ H3, float* __restrict__ S, int n) {
    int i = blockIdx.x * 256 + threadIdx.x;   // over N*64
    if (i < n * 64) {
        int r = i >> 6;
        S[i] = H3[i + (size_t)r * 64] + H3[i + (size_t)r * 64 + 64];
    }
}

// ---------------- CSR build ----------------
__global__ __launch_bounds__(256)
void csr_count(const int* __restrict__ DST, int* __restrict__ deg, int E_) {
    int e = blockIdx.x * 256 + threadIdx.x;
    if (e < E_) atomicAdd(&deg[DST[e]], 1);
}

__global__ __launch_bounds__(256)
void scan1(const int* __restrict__ deg, int* __restrict__ off,
           int* __restrict__ bsum, int n) {
    __shared__ int s[256];
    int tid = threadIdx.x;
    int i = blockIdx.x * 256 + tid;
    int v = (i < n) ? deg[i] : 0;
    s[tid] = v;
    __syncthreads();
    for (int d = 1; d < 256; d <<= 1) {
        int t = (tid >= d) ? s[tid - d] : 0;
        __syncthreads();
        if (tid >= d) s[tid] += t;
        __syncthreads();
    }
    if (i < n) off[i] = s[tid] - v;
    if (tid == 255) bsum[blockIdx.x] = s[255];
}

__global__ __launch_bounds__(256)
void scan2(int* __restrict__ bsum, int nb) {
    __shared__ int s[256];
    int tid = threadIdx.x;
    int v = (tid < nb) ? bsum[tid] : 0;
    s[tid] = v;
    __syncthreads();
    for (int d = 1; d < 256; d <<= 1) {
        int t = (tid >= d) ? s[tid - d] : 0;
        __syncthreads();
        if (tid >= d) s[tid] += t;
        __syncthreads();
    }
    if (tid < nb) bsum[tid] = s[tid] - v;
}

__global__ __launch_bounds__(256)
void scan3(int* __restrict__ off, int* __restrict__ pos,
           const int* __restrict__ bsum, const int* __restrict__ deg, int n) {
    int i = blockIdx.x * 256 + threadIdx.x;
    if (i < n) {
        int o = off[i] + bsum[blockIdx.x];
        off[i] = o;
        pos[i] = o;
        if (i == n - 1) off[n] = o + deg[i];
    }
}

// Fill CSR: src index + edge attrs gathered into CSR order as bf16 (32B/edge).
__global__ __launch_bounds__(256)
void csr_fill(const int* __restrict__ SRC, const int* __restrict__ DST,
              const float* __restrict__ EA, int* __restrict__ pos,
              int* __restrict__ csrsrc, uint4* __restrict__ EABS, int E_) {
    int e = blockIdx.x * 256 + threadIdx.x;
    if (e < E_) {
        int d = DST[e];
        int j = atomicAdd(&pos[d], 1);
        csrsrc[j] = SRC[e];
        const float4* ea4 = (const float4*)(EA + (size_t)e * 16);
        float4 q0 = ea4[0], q1 = ea4[1], q2 = ea4[2], q3 = ea4[3];
        uint4 o0, o1;
        o0.x = pack2(q0.x, q0.y); o0.y = pack2(q0.z, q0.w);
        o0.z = pack2(q1.x, q1.y); o0.w = pack2(q1.z, q1.w);
        o1.x = pack2(q2.x, q2.y); o1.y = pack2(q2.z, q2.w);
        o1.z = pack2(q3.x, q3.y); o1.w = pack2(q3.z, q3.w);
        EABS[(size_t)2 * j] = o0;
        EABS[(size_t)2 * j + 1] = o1;
    }
}

// ---------------- gather aggregation ----------------
#define UNPACK16(p, q, av)                                   \
    float av[16] = {b2f(p.x & 0xffff), b2f(p.x >> 16),       \
                    b2f(p.y & 0xffff), b2f(p.y >> 16),       \
                    b2f(p.z & 0xffff), b2f(p.z >> 16),       \
                    b2f(p.w & 0xffff), b2f(p.w >> 16),       \
                    b2f(q.x & 0xffff), b2f(q.x >> 16),       \
                    b2f(q.y & 0xffff), b2f(q.y >> 16),       \
                    b2f(q.z & 0xffff), b2f(q.z >> 16),       \
                    b2f(q.w & 0xffff), b2f(q.w >> 16)}

// din=128: one wave per node; lane handles cols c, c+64 for both signs.
__global__ __launch_bounds__(256)
void agg_gather128(const int* __restrict__ CSRS, const int* __restrict__ OFF,
                   const uint4* __restrict__ EABS, const float* __restrict__ WE,
                   const float* __restrict__ BE,
                   const unsigned short* __restrict__ HB,
                   float* __restrict__ AGG, int n) {
    const int lane = threadIdx.x & 63;
    const int node = blockIdx.x * 4 + (threadIdx.x >> 6);
    if (node >= n) return;
    const int c = lane;
    float w0[16], w1[16];
#pragma unroll
    for (int k = 0; k < 16; ++k) {
        w0[k] = WE[k * 128 + c];
        w1[k] = WE[k * 128 + c + 64];
    }
    const float be0 = BE[c], be1 = BE[c + 64];
    float a00 = 0.f, a01 = 0.f, a10 = 0.f, a11 = 0.f;  // [sign][half]
    const int j0 = OFF[node], j1 = OFF[node + 1];
#pragma unroll 2
    for (int j = j0; j < j1; ++j) {
        int src = CSRS[j];
        uint4 p = EABS[(size_t)2 * j], q = EABS[(size_t)2 * j + 1];
        UNPACK16(p, q, av);
        float e0 = be0, e1 = be1;
#pragma unroll
        for (int k = 0; k < 16; ++k) {
            e0 += av[k] * w0[k];
            e1 += av[k] * w1[k];
        }
        const unsigned short* h = HB + (size_t)(2 * src) * 128;
        a00 += fmaxf(b2f(h[c]) + e0, 0.f);
        a01 += fmaxf(b2f(h[c + 64]) + e1, 0.f);
        a10 += fmaxf(b2f(h[128 + c]) + e0, 0.f);
        a11 += fmaxf(b2f(h[128 + c + 64]) + e1, 0.f);
    }
    float* arow = AGG + (size_t)(2 * node) * 128;
    arow[c] = a00;
    arow[c + 64] = a01;
    arow[128 + c] = a10;
    arow[128 + c + 64] = a11;
}

// din=16: half-wave (32 lanes) per node: s = (l>>4)&1, c = l&15.
__global__ __launch_bounds__(256)
void agg_gather16(const int* __restrict__ CSRS, const int* __restrict__ OFF,
                  const uint4* __restrict__ EABS, const float* __restrict__ WE,
                  const float* __restrict__ BE,
                  const unsigned short* __restrict__ HB,
                  float* __restrict__ AGG, int n) {
    const int l = threadIdx.x & 31;
    const int node = blockIdx.x * 8 + (threadIdx.x >> 5);
    if (node >= n) return;
    const int s = l >> 4;
    const int c = l & 15;
    float w[16];
#pragma unroll
    for (int k = 0; k < 16; ++k) w[k] = WE[k * 16 + c];
    const float bev = BE[c];
    float acc = 0.f;
    const int j0 = OFF[node], j1 = OFF[node + 1];
#pragma unroll 2
    for (int j = j0; j < j1; ++j) {
        int src = CSRS[j];
        uint4 p = EABS[(size_t)2 * j], q = EABS[(size_t)2 * j + 1];
        UNPACK16(p, q, av);
        float ec = bev;
#pragma unroll
        for (int k = 0; k < 16; ++k) ec += av[k] * w[k];
        float hv = b2f(HB[(size_t)(2 * src + s) * 16 + c]);
        acc += fmaxf(hv + ec, 0.f);
    }
    AGG[(size_t)(2 * node + s) * 16 + c] = acc;
}

// Fused node MLP: OUT = maybe_relu( relu((X [+AGG]) @ W1 + b1) @ W2 + b2 )
// Optionally also writes a bf16 copy of OUT (for the next gather pass).
template <int DIN, int DOUT, bool RELU_OUT, bool HAS_AGG, bool WRITE_B>
__global__ __launch_bounds__(256)
void node_mlp(const float* __restrict__ X, const float* __restrict__ AGG,
              const float* __restrict__ W1, const float* __restrict__ B1,
              const float* __restrict__ W2, const float* __restrict__ B2,
              float* __restrict__ OUT, unsigned short* __restrict__ OUTB,
              int rows) {
    __shared__ float sW1[DIN * DHID];
    __shared__ float sX[32 * DIN];
    __shared__ float sH[32 * DHID];
    __shared__ float sB1[DHID];
    const int tid = threadIdx.x;
    for (int i = tid; i < DIN * DHID; i += 256) sW1[i] = W1[i];
    if (tid < DHID) sB1[tid] = B1[tid];

    for (int row0 = blockIdx.x * 32; row0 < rows; row0 += gridDim.x * 32) {
        __syncthreads();
        // stage X (+AGG) tile via float4
        constexpr int DIN4 = DIN / 4;
        for (int i = tid; i < 32 * DIN4; i += 256) {
            int r = i / DIN4, k4 = i % DIN4;
            int gr = row0 + r;
            float4 v = make_float4(0.f, 0.f, 0.f, 0.f);
            if (gr < rows) {
                v = ((const float4*)X)[(size_t)gr * DIN4 + k4];
                if (HAS_AGG) {
                    float4 a = ((const float4*)AGG)[(size_t)gr * DIN4 + k4];
                    v.x += a.x; v.y += a.y; v.z += a.z; v.w += a.w;
                }
            }
            ((float4*)sX)[i] = v;
        }
        __syncthreads();
        {
            const int c = tid & 63;
            const int r0 = tid >> 6;
            float acc[8][2];
#pragma unroll
            for (int j = 0; j < 8; ++j) {
                acc[j][0] = sB1[c];
                acc[j][1] = sB1[c + 64];
            }
#pragma unroll
            for (int k = 0; k < DIN; ++k) {
                float wa = sW1[k * DHID + c];
                float wb = sW1[k * DHID + c + 64];
#pragma unroll
                for (int j = 0; j < 8; ++j) {
                    float xv = sX[(r0 + 4 * j) * DIN + k];
                    acc[j][0] += xv * wa;
                    acc[j][1] += xv * wb;
                }
            }
#pragma unroll
            for (int j = 0; j < 8; ++j) {
                int r = r0 + 4 * j;
                sH[r * DHID + c] = fmaxf(acc[j][0], 0.f);
                sH[r * DHID + c + 64] = fmaxf(acc[j][1], 0.f);
            }
        }
        __syncthreads();
        {
            constexpr int HALF = DOUT / 2;
            constexpr int RP = 256 / HALF;
            constexpr int ITER = 32 / RP;
            const int c = tid % HALF;
            const int r0 = tid / HALF;
            float acc[ITER][2];
            const float bz0 = B2[c], bz1 = B2[c + HALF];
#pragma unroll
            for (int j = 0; j < ITER; ++j) {
                acc[j][0] = bz0;
                acc[j][1] = bz1;
            }
#pragma unroll 4
            for (int k = 0; k < DHID; ++k) {
                float wa = W2[k * DOUT + c];
                float wb = W2[k * DOUT + c + HALF];
#pragma unroll
                for (int j = 0; j < ITER; ++j) {
                    float hv = sH[(r0 + RP * j) * DHID + k];
                    acc[j][0] += hv * wa;
                    acc[j][1] += hv * wb;
                }
            }
#pragma unroll
            for (int j = 0; j < ITER; ++j) {
                int gr = row0 + r0 + RP * j;
                if (gr < rows) {
                    float o0 = acc[j][0], o1 = acc[j][1];
                    if (RELU_OUT) {
                        o0 = fmaxf(o0, 0.f);
                        o1 = fmaxf(o1, 0.f);
                    }
                    OUT[(size_t)gr * DOUT + c] = o0;
                    OUT[(size_t)gr * DOUT + c + HALF] = o1;
                    if (WRITE_B) {
                        OUTB[(size_t)gr * DOUT + c] = f2b(o0);
                        OUTB[(size_t)gr * DOUT + c + HALF] = f2b(o1);
                    }
                }
            }
        }
    }
}

extern "C" void kernel_launch(void* const* d_in, const int* in_sizes, int n_in,
                              void* d_out, int out_size, void* d_ws, size_t ws_size,
                              hipStream_t stream) {
    const float* x = (const float*)d_in[0];
    const float* ea = (const float*)d_in[1];
    const int* esrc = (const int*)d_in[2];
    const int* edst = (const int*)d_in[3];
    const float* we0 = (const float*)d_in[4];
    const float* be0 = (const float*)d_in[5];
    const float* w10 = (const float*)d_in[6];
    const float* b10 = (const float*)d_in[7];
    const float* w20 = (const float*)d_in[8];
    const float* b20 = (const float*)d_in[9];
    const float* we1 = (const float*)d_in[10];
    const float* be1 = (const float*)d_in[11];
    const float* w11 = (const float*)d_in[12];
    const float* b11 = (const float*)d_in[13];
    const float* w21 = (const float*)d_in[14];
    const float* b21 = (const float*)d_in[15];
    const float* we2 = (const float*)d_in[16];
    const float* be2 = (const float*)d_in[17];
    const float* w12 = (const float*)d_in[18];
    const float* b12 = (const float*)d_in[19];
    const float* w22 = (const float*)d_in[20];
    const float* b22 = (const float*)d_in[21];
    const float* rw1 = (const float*)d_in[22];
    const float* rb1 = (const float*)d_in[23];
    const float* rw2 = (const float*)d_in[24];
    const float* rb2 = (const float*)d_in[25];

    const int N = in_sizes[0] / 16;
    const int E = in_sizes[2];
    const int M = 2 * N;

    float* HA = (float*)d_ws;                        // M*128 f32
    float* HB = HA + (size_t)M * 128;                // M*128 f32
    float* AG = HB + (size_t)M * 128;                // M*128 f32
    unsigned short* Hb = (unsigned short*)(AG + (size_t)M * 128);  // M*128 bf16
    unsigned short* EABS = Hb + (size_t)M * 128;     // E*16 bf16, CSR order
    int* deg = (int*)(EABS + (size_t)E * 16);        // N
    int* off = deg + N;                              // N+1
    int* pos = off + N + 1;                          // N
    int* bsum = pos + N;                             // 256
    int* csrsrc = bsum + 256;                        // E

    const int ntiles = (M + 31) / 32;
    const int eblocks = (E + 255) / 256;
    const int nblocks = (N + 255) / 256;

    // ---- CSR build (once; shared by all 3 layers) ----
    hipMemsetAsync(deg, 0, (size_t)N * sizeof(int), stream);
    csr_count<<<eblocks, 256, 0, stream>>>(edst, deg, E);
    scan1<<<nblocks, 256, 0, stream>>>(deg, off, bsum, N);
    scan2<<<1, 256, 0, stream>>>(bsum, nblocks);
    scan3<<<nblocks, 256, 0, stream>>>(off, pos, bsum, deg, N);
    csr_fill<<<eblocks, 256, 0, stream>>>(esrc, edst, ea, pos, csrsrc,
                                          (uint4*)EABS, E);

    // H0 (M x 16), f32 + bf16 (bf16 aliases Hb's first M*16)
    init_h0<<<(N * 16 + 255) / 256, 256, 0, stream>>>(x, HA, Hb, N);

    // ---- layer 0 (din=16 -> 128) ----
    agg_gather16<<<(N + 7) / 8, 256, 0, stream>>>(csrsrc, off, (const uint4*)EABS,
                                                  we0, be0, Hb, AG, N);
    node_mlp<16, 128, true, true, true><<<ntiles, 256, 0, stream>>>(
        HA, AG, w10, b10, w20, b20, HB, Hb, M);

    // ---- layer 1 (128 -> 128) ----
    agg_gather128<<<(N + 3) / 4, 256, 0, stream>>>(csrsrc, off, (const uint4*)EABS,
                                                   we1, be1, Hb, AG, N);
    node_mlp<128, 128, true, true, true><<<ntiles, 256, 0, stream>>>(
        HB, AG, w11, b11, w21, b21, HA, Hb, M);

    // ---- layer 2 (128 -> 64) ----
    agg_gather128<<<(N + 3) / 4, 256, 0, stream>>>(csrsrc, off, (const uint4*)EABS,
                                                   we2, be2, Hb, AG, N);
    node_mlp<128, 64, false, true, false><<<ntiles, 256, 0, stream>>>(
        HA, AG, w12, b12, w22, b22, HB, nullptr, M);

    // ---- sign sum + readout (64 -> 128 -> 16) ----
    sum_signs<<<(N * 64 + 255) / 256, 256, 0, stream>>>(HB, AG, N);
    node_mlp<64, 16, false, false, false><<<(N + 31) / 32, 256, 0, stream>>>(
        AG, nullptr, rw1, rb1, rw2, rb2, (float*)d_out, nullptr, N);
}

// Round 5
// 1051.918 us; speedup vs baseline: 3.2266x; 1.1535x over previous
//
#include <hip/hip_runtime.h>

// SignNet GINE: 3 layers, signs batched as 2N interleaved rows (2i=+x, 2i+1=-x).
// CSR gather aggregation; gather path: bf16 H + CSR-sorted bf16 edge attrs,
// edge embedding via v_dot2_f32_bf16 with hi/lo-split bf16 weights (f32-grade).
constexpr int DHID = 128;

__device__ __forceinline__ float b2f(unsigned short u) {
    union { unsigned int i; float f; } v;
    v.i = ((unsigned int)u) << 16;
    return v.f;
}
__device__ __forceinline__ unsigned short f2b(float f) {
    union { float f; unsigned int i; } v;
    v.f = f;
    unsigned int x = v.i;
    return (unsigned short)((x + 0x7fff + ((x >> 16) & 1)) >> 16);
}
__device__ __forceinline__ unsigned int pack2(float a, float b) {
    return (unsigned int)f2b(a) | ((unsigned int)f2b(b) << 16);
}
// residual after bf16 rounding
__device__ __forceinline__ float bres(float w) { return w - b2f(f2b(w)); }
// acc += a.bf16[0]*b.bf16[0] + a.bf16[1]*b.bf16[1]  (f32 accumulate)
__device__ __forceinline__ void dot2b(float& acc, unsigned int a, unsigned int b) {
    asm("v_dot2_f32_bf16 %0, %1, %2, %0" : "+v"(acc) : "v"(a), "v"(b));
}

__global__ __launch_bounds__(256)
void init_h0(const float* __restrict__ x, float* __restrict__ H0,
             unsigned short* __restrict__ H0B, int n) {
    int i = blockIdx.x * 256 + threadIdx.x;   // over N*16
    if (i < n * 16) {
        int r = i >> 4, c = i & 15;
        float v = x[i];
        H0[(size_t)(2 * r) * 16 + c] = v;
        H0[(size_t)(2 * r + 1) * 16 + c] = -v;
        H0B[(size_t)(2 * r) * 16 + c] = f2b(v);
        H0B[(size_t)(2 * r + 1) * 16 + c] = f2b(-v);
    }
}

__global__ __launch_bounds__(256)
void sum_signs(const float* __restrict__ H3, float* __restrict__ S, int n) {
    int i = blockIdx.x * 256 + threadIdx.x;   // over N*64
    if (i < n * 64) {
        int r = i >> 6;
        S[i] = H3[i + (size_t)r * 64] + H3[i + (size_t)r * 64 + 64];
    }
}

// ---------------- CSR build ----------------
__global__ __launch_bounds__(256)
void csr_count(const int* __restrict__ DST, int* __restrict__ deg, int E_) {
    int e = blockIdx.x * 256 + threadIdx.x;
    if (e < E_) atomicAdd(&deg[DST[e]], 1);
}

__global__ __launch_bounds__(256)
void scan1(const int* __restrict__ deg, int* __restrict__ off,
           int* __restrict__ bsum, int n) {
    __shared__ int s[256];
    int tid = threadIdx.x;
    int i = blockIdx.x * 256 + tid;
    int v = (i < n) ? deg[i] : 0;
    s[tid] = v;
    __syncthreads();
    for (int d = 1; d < 256; d <<= 1) {
        int t = (tid >= d) ? s[tid - d] : 0;
        __syncthreads();
        if (tid >= d) s[tid] += t;
        __syncthreads();
    }
    if (i < n) off[i] = s[tid] - v;
    if (tid == 255) bsum[blockIdx.x] = s[255];
}

__global__ __launch_bounds__(256)
void scan2(int* __restrict__ bsum, int nb) {
    __shared__ int s[256];
    int tid = threadIdx.x;
    int v = (tid < nb) ? bsum[tid] : 0;
    s[tid] = v;
    __syncthreads();
    for (int d = 1; d < 256; d <<= 1) {
        int t = (tid >= d) ? s[tid - d] : 0;
        __syncthreads();
        if (tid >= d) s[tid] += t;
        __syncthreads();
    }
    if (tid < nb) bsum[tid] = s[tid] - v;
}

__global__ __launch_bounds__(256)
void scan3(int* __restrict__ off, int* __restrict__ pos,
           const int* __restrict__ bsum, const int* __restrict__ deg, int n) {
    int i = blockIdx.x * 256 + threadIdx.x;
    if (i < n) {
        int o = off[i] + bsum[blockIdx.x];
        off[i] = o;
        pos[i] = o;
        if (i == n - 1) off[n] = o + deg[i];
    }
}

// Fill CSR: src index + edge attrs gathered into CSR order as bf16 (32B/edge).
__global__ __launch_bounds__(256)
void csr_fill(const int* __restrict__ SRC, const int* __restrict__ DST,
              const float* __restrict__ EA, int* __restrict__ pos,
              int* __restrict__ csrsrc, uint4* __restrict__ EABS, int E_) {
    int e = blockIdx.x * 256 + threadIdx.x;
    if (e < E_) {
        int d = DST[e];
        int j = atomicAdd(&pos[d], 1);
        csrsrc[j] = SRC[e];
        const float4* ea4 = (const float4*)(EA + (size_t)e * 16);
        float4 q0 = ea4[0], q1 = ea4[1], q2 = ea4[2], q3 = ea4[3];
        uint4 o0, o1;
        o0.x = pack2(q0.x, q0.y); o0.y = pack2(q0.z, q0.w);
        o0.z = pack2(q1.x, q1.y); o0.w = pack2(q1.z, q1.w);
        o1.x = pack2(q2.x, q2.y); o1.y = pack2(q2.z, q2.w);
        o1.z = pack2(q3.x, q3.y); o1.w = pack2(q3.z, q3.w);
        EABS[(size_t)2 * j] = o0;
        EABS[(size_t)2 * j + 1] = o1;
    }
}

// ---------------- gather aggregation ----------------
// din=128: one wave per node; lane handles cols c, c+64 for both signs.
__global__ __launch_bounds__(256)
void agg_gather128(const int* __restrict__ CSRS, const int* __restrict__ OFF,
                   const uint4* __restrict__ EABS, const float* __restrict__ WE,
                   const float* __restrict__ BE,
                   const unsigned short* __restrict__ HB,
                   float* __restrict__ AGG, int n) {
    const int lane = threadIdx.x & 63;
    const int node = blockIdx.x * 4 + (threadIdx.x >> 6);
    if (node >= n) return;
    const int c = lane;
    // hi/lo-split packed bf16 weight pairs along k (col c and col c+64)
    unsigned int w0h[8], w0l[8], w1h[8], w1l[8];
#pragma unroll
    for (int t = 0; t < 8; ++t) {
        float a0 = WE[(2 * t) * 128 + c], a1 = WE[(2 * t + 1) * 128 + c];
        float b0 = WE[(2 * t) * 128 + c + 64], b1 = WE[(2 * t + 1) * 128 + c + 64];
        w0h[t] = pack2(a0, a1);
        w0l[t] = pack2(bres(a0), bres(a1));
        w1h[t] = pack2(b0, b1);
        w1l[t] = pack2(bres(b0), bres(b1));
    }
    const float be0 = BE[c], be1 = BE[c + 64];
    float a00 = 0.f, a01 = 0.f, a10 = 0.f, a11 = 0.f;  // [sign][half]
    const int j0 = OFF[node], j1 = OFF[node + 1];
#pragma unroll 4
    for (int j = j0; j < j1; ++j) {
        int src = CSRS[j];
        uint4 p = EABS[(size_t)2 * j], q = EABS[(size_t)2 * j + 1];
        float e0 = be0, e1 = be1;
        dot2b(e0, p.x, w0h[0]); dot2b(e0, p.y, w0h[1]);
        dot2b(e0, p.z, w0h[2]); dot2b(e0, p.w, w0h[3]);
        dot2b(e0, q.x, w0h[4]); dot2b(e0, q.y, w0h[5]);
        dot2b(e0, q.z, w0h[6]); dot2b(e0, q.w, w0h[7]);
        dot2b(e0, p.x, w0l[0]); dot2b(e0, p.y, w0l[1]);
        dot2b(e0, p.z, w0l[2]); dot2b(e0, p.w, w0l[3]);
        dot2b(e0, q.x, w0l[4]); dot2b(e0, q.y, w0l[5]);
        dot2b(e0, q.z, w0l[6]); dot2b(e0, q.w, w0l[7]);
        dot2b(e1, p.x, w1h[0]); dot2b(e1, p.y, w1h[1]);
        dot2b(e1, p.z, w1h[2]); dot2b(e1, p.w, w1h[3]);
        dot2b(e1, q.x, w1h[4]); dot2b(e1, q.y, w1h[5]);
        dot2b(e1, q.z, w1h[6]); dot2b(e1, q.w, w1h[7]);
        dot2b(e1, p.x, w1l[0]); dot2b(e1, p.y, w1l[1]);
        dot2b(e1, p.z, w1l[2]); dot2b(e1, p.w, w1l[3]);
        dot2b(e1, q.x, w1l[4]); dot2b(e1, q.y, w1l[5]);
        dot2b(e1, q.z, w1l[6]); dot2b(e1, q.w, w1l[7]);
        const unsigned short* h = HB + (size_t)(2 * src) * 128;
        a00 += fmaxf(b2f(h[c]) + e0, 0.f);
        a01 += fmaxf(b2f(h[c + 64]) + e1, 0.f);
        a10 += fmaxf(b2f(h[128 + c]) + e0, 0.f);
        a11 += fmaxf(b2f(h[128 + c + 64]) + e1, 0.f);
    }
    float* arow = AGG + (size_t)(2 * node) * 128;
    arow[c] = a00;
    arow[c + 64] = a01;
    arow[128 + c] = a10;
    arow[128 + c + 64] = a11;
}

// din=16: half-wave (32 lanes) per node: s = (l>>4)&1, c = l&15.
__global__ __launch_bounds__(256)
void agg_gather16(const int* __restrict__ CSRS, const int* __restrict__ OFF,
                  const uint4* __restrict__ EABS, const float* __restrict__ WE,
                  const float* __restrict__ BE,
                  const unsigned short* __restrict__ HB,
                  float* __restrict__ AGG, int n) {
    const int l = threadIdx.x & 31;
    const int node = blockIdx.x * 8 + (threadIdx.x >> 5);
    if (node >= n) return;
    const int s = l >> 4;
    const int c = l & 15;
    unsigned int wh[8], wl[8];
#pragma unroll
    for (int t = 0; t < 8; ++t) {
        float a0 = WE[(2 * t) * 16 + c], a1 = WE[(2 * t + 1) * 16 + c];
        wh[t] = pack2(a0, a1);
        wl[t] = pack2(bres(a0), bres(a1));
    }
    const float bev = BE[c];
    float acc = 0.f;
    const int j0 = OFF[node], j1 = OFF[node + 1];
#pragma unroll 4
    for (int j = j0; j < j1; ++j) {
        int src = CSRS[j];
        uint4 p = EABS[(size_t)2 * j], q = EABS[(size_t)2 * j + 1];
        float ec = bev;
        dot2b(ec, p.x, wh[0]); dot2b(ec, p.y, wh[1]);
        dot2b(ec, p.z, wh[2]); dot2b(ec, p.w, wh[3]);
        dot2b(ec, q.x, wh[4]); dot2b(ec, q.y, wh[5]);
        dot2b(ec, q.z, wh[6]); dot2b(ec, q.w, wh[7]);
        dot2b(ec, p.x, wl[0]); dot2b(ec, p.y, wl[1]);
        dot2b(ec, p.z, wl[2]); dot2b(ec, p.w, wl[3]);
        dot2b(ec, q.x, wl[4]); dot2b(ec, q.y, wl[5]);
        dot2b(ec, q.z, wl[6]); dot2b(ec, q.w, wl[7]);
        float hv = b2f(HB[(size_t)(2 * src + s) * 16 + c]);
        acc += fmaxf(hv + ec, 0.f);
    }
    AGG[(size_t)(2 * node + s) * 16 + c] = acc;
}

// Fused node MLP: OUT = maybe_relu( relu((X [+AGG]) @ W1 + b1) @ W2 + b2 )
// W1/W2 read direct from global (L1/L2-resident, broadcast); X/H tiles in LDS.
template <int DIN, int DOUT, bool RELU_OUT, bool HAS_AGG, bool WRITE_B>
__global__ __launch_bounds__(256)
void node_mlp(const float* __restrict__ X, const float* __restrict__ AGG,
              const float* __restrict__ W1, const float* __restrict__ B1,
              const float* __restrict__ W2, const float* __restrict__ B2,
              float* __restrict__ OUT, unsigned short* __restrict__ OUTB,
              int rows) {
    __shared__ float sX[32 * DIN];
    __shared__ float sH[32 * DHID];
    const int tid = threadIdx.x;

    for (int row0 = blockIdx.x * 32; row0 < rows; row0 += gridDim.x * 32) {
        __syncthreads();
        // stage X (+AGG) tile via float4
        constexpr int DIN4 = DIN / 4;
        for (int i = tid; i < 32 * DIN4; i += 256) {
            int r = i / DIN4, k4 = i % DIN4;
            int gr = row0 + r;
            float4 v = make_float4(0.f, 0.f, 0.f, 0.f);
            if (gr < rows) {
                v = ((const float4*)X)[(size_t)gr * DIN4 + k4];
                if (HAS_AGG) {
                    float4 a = ((const float4*)AGG)[(size_t)gr * DIN4 + k4];
                    v.x += a.x; v.y += a.y; v.z += a.z; v.w += a.w;
                }
            }
            ((float4*)sX)[i] = v;
        }
        __syncthreads();
        // hidden = relu(sX @ W1 + b1): lane cols (c, c+64), rows r0+4j
        {
            const int c = tid & 63;
            const int r0 = tid >> 6;
            float acc[8][2];
            const float b1a = B1[c], b1b = B1[c + 64];
#pragma unroll
            for (int j = 0; j < 8; ++j) {
                acc[j][0] = b1a;
                acc[j][1] = b1b;
            }
#pragma unroll 2
            for (int k4 = 0; k4 < DIN / 4; ++k4) {
                const int k = 4 * k4;
                float wa[4], wb[4];
#pragma unroll
                for (int kk = 0; kk < 4; ++kk) {
                    wa[kk] = W1[(k + kk) * DHID + c];
                    wb[kk] = W1[(k + kk) * DHID + c + 64];
                }
#pragma unroll
                for (int j = 0; j < 8; ++j) {
                    float4 xv = ((const float4*)sX)[((r0 + 4 * j) * DIN + k) >> 2];
                    acc[j][0] += xv.x * wa[0]; acc[j][1] += xv.x * wb[0];
                    acc[j][0] += xv.y * wa[1]; acc[j][1] += xv.y * wb[1];
                    acc[j][0] += xv.z * wa[2]; acc[j][1] += xv.z * wb[2];
                    acc[j][0] += xv.w * wa[3]; acc[j][1] += xv.w * wb[3];
                }
            }
#pragma unroll
            for (int j = 0; j < 8; ++j) {
                int r = r0 + 4 * j;
                sH[r * DHID + c] = fmaxf(acc[j][0], 0.f);
                sH[r * DHID + c + 64] = fmaxf(acc[j][1], 0.f);
            }
        }
        __syncthreads();
        // out = sH @ W2 + b2
        {
            constexpr int HALF = DOUT / 2;
            constexpr int RP = 256 / HALF;
            constexpr int ITER = 32 / RP;
            const int c = tid % HALF;
            const int r0 = tid / HALF;
            float acc[ITER][2];
            const float bz0 = B2[c], bz1 = B2[c + HALF];
#pragma unroll
            for (int j = 0; j < ITER; ++j) {
                acc[j][0] = bz0;
                acc[j][1] = bz1;
            }
#pragma unroll 2
            for (int k4 = 0; k4 < DHID / 4; ++k4) {
                const int k = 4 * k4;
                float wa[4], wb[4];
#pragma unroll
                for (int kk = 0; kk < 4; ++kk) {
                    wa[kk] = W2[(k + kk) * DOUT + c];
                    wb[kk] = W2[(k + kk) * DOUT + c + HALF];
                }
#pragma unroll
                for (int j = 0; j < ITER; ++j) {
                    float4 hv = ((const float4*)sH)[((r0 + RP * j) * DHID + k) >> 2];
                    acc[j][0] += hv.x * wa[0]; acc[j][1] += hv.x * wb[0];
                    acc[j][0] += hv.y * wa[1]; acc[j][1] += hv.y * wb[1];
                    acc[j][0] += hv.z * wa[2]; acc[j][1] += hv.z * wb[2];
                    acc[j][0] += hv.w * wa[3]; acc[j][1] += hv.w * wb[3];
                }
            }
#pragma unroll
            for (int j = 0; j < ITER; ++j) {
                int gr = row0 + r0 + RP * j;
                if (gr < rows) {
                    float o0 = acc[j][0], o1 = acc[j][1];
                    if (RELU_OUT) {
                        o0 = fmaxf(o0, 0.f);
                        o1 = fmaxf(o1, 0.f);
                    }
                    OUT[(size_t)gr * DOUT + c] = o0;
                    OUT[(size_t)gr * DOUT + c + HALF] = o1;
                    if (WRITE_B) {
                        OUTB[(size_t)gr * DOUT + c] = f2b(o0);
                        OUTB[(size_t)gr * DOUT + c + HALF] = f2b(o1);
                    }
                }
            }
        }
    }
}

extern "C" void kernel_launch(void* const* d_in, const int* in_sizes, int n_in,
                              void* d_out, int out_size, void* d_ws, size_t ws_size,
                              hipStream_t stream) {
    const float* x = (const float*)d_in[0];
    const float* ea = (const float*)d_in[1];
    const int* esrc = (const int*)d_in[2];
    const int* edst = (const int*)d_in[3];
    const float* we0 = (const float*)d_in[4];
    const float* be0 = (const float*)d_in[5];
    const float* w10 = (const float*)d_in[6];
    const float* b10 = (const float*)d_in[7];
    const float* w20 = (const float*)d_in[8];
    const float* b20 = (const float*)d_in[9];
    const float* we1 = (const float*)d_in[10];
    const float* be1 = (const float*)d_in[11];
    const float* w11 = (const float*)d_in[12];
    const float* b11 = (const float*)d_in[13];
    const float* w21 = (const float*)d_in[14];
    const float* b21 = (const float*)d_in[15];
    const float* we2 = (const float*)d_in[16];
    const float* be2 = (const float*)d_in[17];
    const float* w12 = (const float*)d_in[18];
    const float* b12 = (const float*)d_in[19];
    const float* w22 = (const float*)d_in[20];
    const float* b22 = (const float*)d_in[21];
    const float* rw1 = (const float*)d_in[22];
    const float* rb1 = (const float*)d_in[23];
    const float* rw2 = (const float*)d_in[24];
    const float* rb2 = (const float*)d_in[25];

    const int N = in_sizes[0] / 16;
    const int E = in_sizes[2];
    const int M = 2 * N;

    float* HA = (float*)d_ws;                        // M*128 f32
    float* HB = HA + (size_t)M * 128;                // M*128 f32
    float* AG = HB + (size_t)M * 128;                // M*128 f32
    unsigned short* Hb = (unsigned short*)(AG + (size_t)M * 128);  // M*128 bf16
    unsigned short* EABS = Hb + (size_t)M * 128;     // E*16 bf16, CSR order
    int* deg = (int*)(EABS + (size_t)E * 16);        // N
    int* off = deg + N;                              // N+1
    int* pos = off + N + 1;                          // N
    int* bsum = pos + N;                             // 256
    int* csrsrc = bsum + 256;                        // E

    const int ntiles = (M + 31) / 32;
    const int eblocks = (E + 255) / 256;
    const int nblocks = (N + 255) / 256;

    // ---- CSR build (once; shared by all 3 layers) ----
    hipMemsetAsync(deg, 0, (size_t)N * sizeof(int), stream);
    csr_count<<<eblocks, 256, 0, stream>>>(edst, deg, E);
    scan1<<<nblocks, 256, 0, stream>>>(deg, off, bsum, N);
    scan2<<<1, 256, 0, stream>>>(bsum, nblocks);
    scan3<<<nblocks, 256, 0, stream>>>(off, pos, bsum, deg, N);
    csr_fill<<<eblocks, 256, 0, stream>>>(esrc, edst, ea, pos, csrsrc,
                                          (uint4*)EABS, E);

    // H0 (M x 16), f32 + bf16
    init_h0<<<(N * 16 + 255) / 256, 256, 0, stream>>>(x, HA, Hb, N);

    // ---- layer 0 (din=16 -> 128) ----
    agg_gather16<<<(N + 7) / 8, 256, 0, stream>>>(csrsrc, off, (const uint4*)EABS,
                                                  we0, be0, Hb, AG, N);
    node_mlp<16, 128, true, true, true><<<ntiles, 256, 0, stream>>>(
        HA, AG, w10, b10, w20, b20, HB, Hb, M);

    // ---- layer 1 (128 -> 128) ----
    agg_gather128<<<(N + 3) / 4, 256, 0, stream>>>(csrsrc, off, (const uint4*)EABS,
                                                   we1, be1, Hb, AG, N);
    node_mlp<128, 128, true, true, true><<<ntiles, 256, 0, stream>>>(
        HB, AG, w11, b11, w21, b21, HA, Hb, M);

    // ---- layer 2 (128 -> 64) ----
    agg_gather128<<<(N + 3) / 4, 256, 0, stream>>>(csrsrc, off, (const uint4*)EABS,
                                                   we2, be2, Hb, AG, N);
    node_mlp<128, 64, false, true, false><<<ntiles, 256, 0, stream>>>(
        HA, AG, w12, b12, w22, b22, HB, nullptr, M);

    // ---- sign sum + readout (64 -> 128 -> 16) ----
    sum_signs<<<(N * 64 + 255) / 256, 256, 0, stream>>>(HB, AG, N);
    node_mlp<64, 16, false, false, false><<<(N + 31) / 32, 256, 0, stream>>>(
        AG, nullptr, rw1, rb1, rw2, rb2, (float*)d_out, nullptr, N);
}

// Round 6
// 1005.548 us; speedup vs baseline: 3.3753x; 1.0461x over previous
//
#include <hip/hip_runtime.h>

// SignNet GINE: 3 layers, signs batched as 2N interleaved rows (2i=+x, 2i+1=-x).
// CSR gather aggregation. agg128: per-node chunks of 16 edges; edge embedding
// e = EA@We + be computed on the MATRIX pipe (mfma_f32_16x16x32_bf16) with
// hi/lo-split We packed into the two K-halves (f32-grade precision).
constexpr int DHID = 128;

typedef __attribute__((ext_vector_type(8))) short bf16x8v;
typedef __attribute__((ext_vector_type(4))) float f32x4v;

__device__ __forceinline__ float b2f(unsigned short u) {
    union { unsigned int i; float f; } v;
    v.i = ((unsigned int)u) << 16;
    return v.f;
}
__device__ __forceinline__ unsigned short f2b(float f) {
    union { float f; unsigned int i; } v;
    v.f = f;
    unsigned int x = v.i;
    return (unsigned short)((x + 0x7fff + ((x >> 16) & 1)) >> 16);
}
__device__ __forceinline__ unsigned int pack2(float a, float b) {
    return (unsigned int)f2b(a) | ((unsigned int)f2b(b) << 16);
}
__device__ __forceinline__ float bres(float w) { return w - b2f(f2b(w)); }
// acc += a.bf16[0]*b.bf16[0] + a.bf16[1]*b.bf16[1]  (f32 accumulate)
__device__ __forceinline__ void dot2b(float& acc, unsigned int a, unsigned int b) {
    asm("v_dot2_f32_bf16 %0, %1, %2, %0" : "+v"(acc) : "v"(a), "v"(b));
}

__global__ __launch_bounds__(256)
void init_h0(const float* __restrict__ x, float* __restrict__ H0,
             unsigned short* __restrict__ H0B, int n) {
    int i = blockIdx.x * 256 + threadIdx.x;   // over N*16
    if (i < n * 16) {
        int r = i >> 4, c = i & 15;
        float v = x[i];
        H0[(size_t)(2 * r) * 16 + c] = v;
        H0[(size_t)(2 * r + 1) * 16 + c] = -v;
        H0B[(size_t)(2 * r) * 16 + c] = f2b(v);
        H0B[(size_t)(2 * r + 1) * 16 + c] = f2b(-v);
    }
}

__global__ __launch_bounds__(256)
void sum_signs(const float* __restrict__ H3, float* __restrict__ S, int n) {
    int i = blockIdx.x * 256 + threadIdx.x;   // over N*64
    if (i < n * 64) {
        int r = i >> 6;
        S[i] = H3[i + (size_t)r * 64] + H3[i + (size_t)r * 64 + 64];
    }
}

// ---------------- CSR build ----------------
__global__ __launch_bounds__(256)
void csr_count(const int* __restrict__ DST, int* __restrict__ deg, int E_) {
    int e = blockIdx.x * 256 + threadIdx.x;
    if (e < E_) atomicAdd(&deg[DST[e]], 1);
}

__global__ __launch_bounds__(256)
void scan1(const int* __restrict__ deg, int* __restrict__ off,
           int* __restrict__ bsum, int n) {
    __shared__ int s[256];
    int tid = threadIdx.x;
    int i = blockIdx.x * 256 + tid;
    int v = (i < n) ? deg[i] : 0;
    s[tid] = v;
    __syncthreads();
    for (int d = 1; d < 256; d <<= 1) {
        int t = (tid >= d) ? s[tid - d] : 0;
        __syncthreads();
        if (tid >= d) s[tid] += t;
        __syncthreads();
    }
    if (i < n) off[i] = s[tid] - v;
    if (tid == 255) bsum[blockIdx.x] = s[255];
}

__global__ __launch_bounds__(256)
void scan2(int* __restrict__ bsum, int nb) {
    __shared__ int s[256];
    int tid = threadIdx.x;
    int v = (tid < nb) ? bsum[tid] : 0;
    s[tid] = v;
    __syncthreads();
    for (int d = 1; d < 256; d <<= 1) {
        int t = (tid >= d) ? s[tid - d] : 0;
        __syncthreads();
        if (tid >= d) s[tid] += t;
        __syncthreads();
    }
    if (tid < nb) bsum[tid] = s[tid] - v;
}

__global__ __launch_bounds__(256)
void scan3(int* __restrict__ off, int* __restrict__ pos,
           const int* __restrict__ bsum, const int* __restrict__ deg, int n) {
    int i = blockIdx.x * 256 + threadIdx.x;
    if (i < n) {
        int o = off[i] + bsum[blockIdx.x];
        off[i] = o;
        pos[i] = o;
        if (i == n - 1) off[n] = o + deg[i];
    }
}

// Fill CSR: src index + edge attrs gathered into CSR order as bf16 (32B/edge).
__global__ __launch_bounds__(256)
void csr_fill(const int* __restrict__ SRC, const int* __restrict__ DST,
              const float* __restrict__ EA, int* __restrict__ pos,
              int* __restrict__ csrsrc, uint4* __restrict__ EABS, int E_) {
    int e = blockIdx.x * 256 + threadIdx.x;
    if (e < E_) {
        int d = DST[e];
        int j = atomicAdd(&pos[d], 1);
        csrsrc[j] = SRC[e];
        const float4* ea4 = (const float4*)(EA + (size_t)e * 16);
        float4 q0 = ea4[0], q1 = ea4[1], q2 = ea4[2], q3 = ea4[3];
        uint4 o0, o1;
        o0.x = pack2(q0.x, q0.y); o0.y = pack2(q0.z, q0.w);
        o0.z = pack2(q1.x, q1.y); o0.w = pack2(q1.z, q1.w);
        o1.x = pack2(q2.x, q2.y); o1.y = pack2(q2.z, q2.w);
        o1.z = pack2(q3.x, q3.y); o1.w = pack2(q3.z, q3.w);
        EABS[(size_t)2 * j] = o0;
        EABS[(size_t)2 * j + 1] = o1;
    }
}

// ---------------- gather aggregation ----------------
// din=128, MFMA edge-embedding. One wave per node; chunks of 16 edges.
// MFMA operand map (16x16x32 bf16): lane%16 = non-K index, k=(lane>>4)*8+i.
//   A: rows = edge slot (0..15); EA has K=16 real values, replicated into
//      k 16..31 (byte offset (grp&1)*16 of the edge's 32B record).
//   B: cols = output col within 16-col block; k<16 -> We_hi, k>=16 -> We_lo.
//   C/D: col = lane&15, edge = (lane>>4)*4 + reg   [verified m89 layout]
__global__ __launch_bounds__(256)
void agg_gather128(const int* __restrict__ CSRS, const int* __restrict__ OFF,
                   const unsigned short* __restrict__ EABS,
                   const float* __restrict__ WE, const float* __restrict__ BE,
                   const unsigned short* __restrict__ HB,
                   float* __restrict__ AGG, int n) {
    const int tid = threadIdx.x;
    const int lane = tid & 63;
    const int node = blockIdx.x * 4 + (tid >> 6);
    if (node >= n) return;
    const int col = lane & 15;
    const int grp = lane >> 4;          // 0..3
    const int klo = (grp & 1) * 8;      // k-offset within the 16 real ks

    // B fragments: 8 col-blocks, each 8 bf16/lane.
    bf16x8v bfrag[8];
#pragma unroll
    for (int cb = 0; cb < 8; ++cb) {
        bf16x8v b;
#pragma unroll
        for (int i = 0; i < 8; ++i) {
            float w = WE[(klo + i) * 128 + cb * 16 + col];
            unsigned short hi = f2b(w);
            unsigned short lo = f2b(bres(w));
            b[i] = (short)(grp >= 2 ? lo : hi);
        }
        bfrag[cb] = b;
    }
    float bias[8];
#pragma unroll
    for (int cb = 0; cb < 8; ++cb) bias[cb] = BE[cb * 16 + col];

    float asum0[8], asum1[8];
#pragma unroll
    for (int cb = 0; cb < 8; ++cb) { asum0[cb] = 0.f; asum1[cb] = 0.f; }

    const int j0 = OFF[node], j1 = OFF[node + 1];
    const char* ebase = (const char*)EABS;

    for (int base = j0; base < j1; base += 16) {
        const int rem = j1 - base;
        // A fragment: edge slot = col, 16B at edge*32 + (grp&1)*16
        uint4 a4 = *(const uint4*)(ebase + ((size_t)(base + col) << 5) +
                                   ((grp & 1) << 4));
        bf16x8v afrag = __builtin_bit_cast(bf16x8v, a4);
        // e = EA @ (We_hi + We_lo) + be  for 16 edges x 128 cols
        f32x4v ev[8];
#pragma unroll
        for (int cb = 0; cb < 8; ++cb) {
            f32x4v c = {bias[cb], bias[cb], bias[cb], bias[cb]};
            ev[cb] = __builtin_amdgcn_mfma_f32_16x16x32_bf16(afrag, bfrag[cb], c,
                                                             0, 0, 0);
        }
        // this group's 4 edges: slots grp*4 + r
        float vmask[4];
        const unsigned short* hp[4];
#pragma unroll
        for (int r = 0; r < 4; ++r) {
            int t = grp * 4 + r;
            bool valid = t < rem;
            vmask[r] = valid ? 1.f : 0.f;
            int ji = valid ? (base + t) : j0;   // safe index
            int src = CSRS[ji];
            hp[r] = HB + (size_t)(2 * src) * 128;
        }
#pragma unroll
        for (int cb = 0; cb < 8; ++cb) {
            float p0 = 0.f, p1 = 0.f;
#pragma unroll
            for (int r = 0; r < 4; ++r) {
                float e = ev[cb][r];
                float h0 = b2f(hp[r][cb * 16 + col]);
                float h1 = b2f(hp[r][128 + cb * 16 + col]);
                p0 += fmaxf(h0 + e, 0.f) * vmask[r];
                p1 += fmaxf(h1 + e, 0.f) * vmask[r];
            }
            // butterfly across the 4 groups (lane bits 4,5)
            p0 += __shfl_xor(p0, 16);
            p0 += __shfl_xor(p0, 32);
            p1 += __shfl_xor(p1, 16);
            p1 += __shfl_xor(p1, 32);
            asum0[cb] += p0;
            asum1[cb] += p1;
        }
    }
    float* arow = AGG + (size_t)(2 * node) * 128;
#pragma unroll
    for (int cb = 0; cb < 8; ++cb) {
        if (grp == (cb & 3)) {
            arow[cb * 16 + col] = asum0[cb];
            arow[128 + cb * 16 + col] = asum1[cb];
        }
    }
}

// din=16: half-wave (32 lanes) per node: s = (l>>4)&1, c = l&15.
__global__ __launch_bounds__(256)
void agg_gather16(const int* __restrict__ CSRS, const int* __restrict__ OFF,
                  const uint4* __restrict__ EABS, const float* __restrict__ WE,
                  const float* __restrict__ BE,
                  const unsigned short* __restrict__ HB,
                  float* __restrict__ AGG, int n) {
    const int l = threadIdx.x & 31;
    const int node = blockIdx.x * 8 + (threadIdx.x >> 5);
    if (node >= n) return;
    const int s = l >> 4;
    const int c = l & 15;
    unsigned int wh[8], wl[8];
#pragma unroll
    for (int t = 0; t < 8; ++t) {
        float a0 = WE[(2 * t) * 16 + c], a1 = WE[(2 * t + 1) * 16 + c];
        wh[t] = pack2(a0, a1);
        wl[t] = pack2(bres(a0), bres(a1));
    }
    const float bev = BE[c];
    float acc = 0.f;
    const int j0 = OFF[node], j1 = OFF[node + 1];
#pragma unroll 4
    for (int j = j0; j < j1; ++j) {
        int src = CSRS[j];
        uint4 p = EABS[(size_t)2 * j], q = EABS[(size_t)2 * j + 1];
        float ec = bev;
        dot2b(ec, p.x, wh[0]); dot2b(ec, p.y, wh[1]);
        dot2b(ec, p.z, wh[2]); dot2b(ec, p.w, wh[3]);
        dot2b(ec, q.x, wh[4]); dot2b(ec, q.y, wh[5]);
        dot2b(ec, q.z, wh[6]); dot2b(ec, q.w, wh[7]);
        dot2b(ec, p.x, wl[0]); dot2b(ec, p.y, wl[1]);
        dot2b(ec, p.z, wl[2]); dot2b(ec, p.w, wl[3]);
        dot2b(ec, q.x, wl[4]); dot2b(ec, q.y, wl[5]);
        dot2b(ec, q.z, wl[6]); dot2b(ec, q.w, wl[7]);
        float hv = b2f(HB[(size_t)(2 * src + s) * 16 + c]);
        acc += fmaxf(hv + ec, 0.f);
    }
    AGG[(size_t)(2 * node + s) * 16 + c] = acc;
}

// Fused node MLP: OUT = maybe_relu( relu((X [+AGG]) @ W1 + b1) @ W2 + b2 )
// W1/W2 read direct from global (L1/L2-resident, broadcast); X/H tiles in LDS.
template <int DIN, int DOUT, bool RELU_OUT, bool HAS_AGG, bool WRITE_B>
__global__ __launch_bounds__(256)
void node_mlp(const float* __restrict__ X, const float* __restrict__ AGG,
              const float* __restrict__ W1, const float* __restrict__ B1,
              const float* __restrict__ W2, const float* __restrict__ B2,
              float* __restrict__ OUT, unsigned short* __restrict__ OUTB,
              int rows) {
    __shared__ float sX[32 * DIN];
    __shared__ float sH[32 * DHID];
    const int tid = threadIdx.x;

    for (int row0 = blockIdx.x * 32; row0 < rows; row0 += gridDim.x * 32) {
        __syncthreads();
        constexpr int DIN4 = DIN / 4;
        for (int i = tid; i < 32 * DIN4; i += 256) {
            int r = i / DIN4, k4 = i % DIN4;
            int gr = row0 + r;
            float4 v = make_float4(0.f, 0.f, 0.f, 0.f);
            if (gr < rows) {
                v = ((const float4*)X)[(size_t)gr * DIN4 + k4];
                if (HAS_AGG) {
                    float4 a = ((const float4*)AGG)[(size_t)gr * DIN4 + k4];
                    v.x += a.x; v.y += a.y; v.z += a.z; v.w += a.w;
                }
            }
            ((float4*)sX)[i] = v;
        }
        __syncthreads();
        {
            const int c = tid & 63;
            const int r0 = tid >> 6;
            float acc[8][2];
            const float b1a = B1[c], b1b = B1[c + 64];
#pragma unroll
            for (int j = 0; j < 8; ++j) {
                acc[j][0] = b1a;
                acc[j][1] = b1b;
            }
#pragma unroll 2
            for (int k4 = 0; k4 < DIN / 4; ++k4) {
                const int k = 4 * k4;
                float wa[4], wb[4];
#pragma unroll
                for (int kk = 0; kk < 4; ++kk) {
                    wa[kk] = W1[(k + kk) * DHID + c];
                    wb[kk] = W1[(k + kk) * DHID + c + 64];
                }
#pragma unroll
                for (int j = 0; j < 8; ++j) {
                    float4 xv = ((const float4*)sX)[((r0 + 4 * j) * DIN + k) >> 2];
                    acc[j][0] += xv.x * wa[0]; acc[j][1] += xv.x * wb[0];
                    acc[j][0] += xv.y * wa[1]; acc[j][1] += xv.y * wb[1];
                    acc[j][0] += xv.z * wa[2]; acc[j][1] += xv.z * wb[2];
                    acc[j][0] += xv.w * wa[3]; acc[j][1] += xv.w * wb[3];
                }
            }
#pragma unroll
            for (int j = 0; j < 8; ++j) {
                int r = r0 + 4 * j;
                sH[r * DHID + c] = fmaxf(acc[j][0], 0.f);
                sH[r * DHID + c + 64] = fmaxf(acc[j][1], 0.f);
            }
        }
        __syncthreads();
        {
            constexpr int HALF = DOUT / 2;
            constexpr int RP = 256 / HALF;
            constexpr int ITER = 32 / RP;
            const int c = tid % HALF;
            const int r0 = tid / HALF;
            float acc[ITER][2];
            const float bz0 = B2[c], bz1 = B2[c + HALF];
#pragma unroll
            for (int j = 0; j < ITER; ++j) {
                acc[j][0] = bz0;
                acc[j][1] = bz1;
            }
#pragma unroll 2
            for (int k4 = 0; k4 < DHID / 4; ++k4) {
                const int k = 4 * k4;
                float wa[4], wb[4];
#pragma unroll
                for (int kk = 0; kk < 4; ++kk) {
                    wa[kk] = W2[(k + kk) * DOUT + c];
                    wb[kk] = W2[(k + kk) * DOUT + c + HALF];
                }
#pragma unroll
                for (int j = 0; j < ITER; ++j) {
                    float4 hv = ((const float4*)sH)[((r0 + RP * j) * DHID + k) >> 2];
                    acc[j][0] += hv.x * wa[0]; acc[j][1] += hv.x * wb[0];
                    acc[j][0] += hv.y * wa[1]; acc[j][1] += hv.y * wb[1];
                    acc[j][0] += hv.z * wa[2]; acc[j][1] += hv.z * wb[2];
                    acc[j][0] += hv.w * wa[3]; acc[j][1] += hv.w * wb[3];
                }
            }
#pragma unroll
            for (int j = 0; j < ITER; ++j) {
                int gr = row0 + r0 + RP * j;
                if (gr < rows) {
                    float o0 = acc[j][0], o1 = acc[j][1];
                    if (RELU_OUT) {
                        o0 = fmaxf(o0, 0.f);
                        o1 = fmaxf(o1, 0.f);
                    }
                    OUT[(size_t)gr * DOUT + c] = o0;
                    OUT[(size_t)gr * DOUT + c + HALF] = o1;
                    if (WRITE_B) {
                        OUTB[(size_t)gr * DOUT + c] = f2b(o0);
                        OUTB[(size_t)gr * DOUT + c + HALF] = f2b(o1);
                    }
                }
            }
        }
    }
}

extern "C" void kernel_launch(void* const* d_in, const int* in_sizes, int n_in,
                              void* d_out, int out_size, void* d_ws, size_t ws_size,
                              hipStream_t stream) {
    const float* x = (const float*)d_in[0];
    const float* ea = (const float*)d_in[1];
    const int* esrc = (const int*)d_in[2];
    const int* edst = (const int*)d_in[3];
    const float* we0 = (const float*)d_in[4];
    const float* be0 = (const float*)d_in[5];
    const float* w10 = (const float*)d_in[6];
    const float* b10 = (const float*)d_in[7];
    const float* w20 = (const float*)d_in[8];
    const float* b20 = (const float*)d_in[9];
    const float* we1 = (const float*)d_in[10];
    const float* be1 = (const float*)d_in[11];
    const float* w11 = (const float*)d_in[12];
    const float* b11 = (const float*)d_in[13];
    const float* w21 = (const float*)d_in[14];
    const float* b21 = (const float*)d_in[15];
    const float* we2 = (const float*)d_in[16];
    const float* be2 = (const float*)d_in[17];
    const float* w12 = (const float*)d_in[18];
    const float* b12 = (const float*)d_in[19];
    const float* w22 = (const float*)d_in[20];
    const float* b22 = (const float*)d_in[21];
    const float* rw1 = (const float*)d_in[22];
    const float* rb1 = (const float*)d_in[23];
    const float* rw2 = (const float*)d_in[24];
    const float* rb2 = (const float*)d_in[25];

    const int N = in_sizes[0] / 16;
    const int E = in_sizes[2];
    const int M = 2 * N;

    float* HA = (float*)d_ws;                        // M*128 f32
    float* HB = HA + (size_t)M * 128;                // M*128 f32
    float* AG = HB + (size_t)M * 128;                // M*128 f32
    unsigned short* Hb = (unsigned short*)(AG + (size_t)M * 128);  // M*128 bf16
    unsigned short* EABS = Hb + (size_t)M * 128;     // E*16 bf16, CSR order
    int* deg = (int*)(EABS + (size_t)E * 16);        // N
    int* off = deg + N;                              // N+1
    int* pos = off + N + 1;                          // N
    int* bsum = pos + N;                             // 256
    int* csrsrc = bsum + 256;                        // E

    const int ntiles = (M + 31) / 32;
    const int eblocks = (E + 255) / 256;
    const int nblocks = (N + 255) / 256;

    // ---- CSR build (once; shared by all 3 layers) ----
    hipMemsetAsync(deg, 0, (size_t)N * sizeof(int), stream);
    csr_count<<<eblocks, 256, 0, stream>>>(edst, deg, E);
    scan1<<<nblocks, 256, 0, stream>>>(deg, off, bsum, N);
    scan2<<<1, 256, 0, stream>>>(bsum, nblocks);
    scan3<<<nblocks, 256, 0, stream>>>(off, pos, bsum, deg, N);
    csr_fill<<<eblocks, 256, 0, stream>>>(esrc, edst, ea, pos, csrsrc,
                                          (uint4*)EABS, E);

    // H0 (M x 16), f32 + bf16
    init_h0<<<(N * 16 + 255) / 256, 256, 0, stream>>>(x, HA, Hb, N);

    // ---- layer 0 (din=16 -> 128) ----
    agg_gather16<<<(N + 7) / 8, 256, 0, stream>>>(csrsrc, off, (const uint4*)EABS,
                                                  we0, be0, Hb, AG, N);
    node_mlp<16, 128, true, true, true><<<ntiles, 256, 0, stream>>>(
        HA, AG, w10, b10, w20, b20, HB, Hb, M);

    // ---- layer 1 (128 -> 128) ----
    agg_gather128<<<(N + 3) / 4, 256, 0, stream>>>(csrsrc, off, EABS,
                                                   we1, be1, Hb, AG, N);
    node_mlp<128, 128, true, true, true><<<ntiles, 256, 0, stream>>>(
        HB, AG, w11, b11, w21, b21, HA, Hb, M);

    // ---- layer 2 (128 -> 64) ----
    agg_gather128<<<(N + 3) / 4, 256, 0, stream>>>(csrsrc, off, EABS,
                                                   we2, be2, Hb, AG, N);
    node_mlp<128, 64, false, true, false><<<ntiles, 256, 0, stream>>>(
        HA, AG, w12, b12, w22, b22, HB, nullptr, M);

    // ---- sign sum + readout (64 -> 128 -> 16) ----
    sum_signs<<<(N * 64 + 255) / 256, 256, 0, stream>>>(HB, AG, N);
    node_mlp<64, 16, false, false, false><<<(N + 31) / 32, 256, 0, stream>>>(
        AG, nullptr, rw1, rb1, rw2, rb2, (float*)d_out, nullptr, N);
}